// Round 1
// baseline (3059.137 us; speedup 1.0000x reference)
//
#include <hip/hip_runtime.h>

// DigitCaps dynamic routing, MI355X.
// Shapes: inputs x[B=64, I=2048, Q=16] fp32; W[J=32, I=2048, P=32, Q=16] fp32.
// out[B=64, J=32, P=32] fp32.
//
// Structure: u_hat[b,j,i,p] = sum_q x[b,i,q] W[j,i,p,q] is RECOMPUTED in each of
// 3 routing passes (never materialized: 512MB). Each pass fuses
//   b_new = b_old + sum_p v*u_hat ; c = softmax_j(b_new) ; s += c*u_hat
// by covering all J within a block. ws holds b_logits [I,B,J], s and v [B,J,P].

namespace {

constexpr int I_DIM = 2048;
constexpr int B_DIM = 64;
constexpr int J_DIM = 32;
constexpr int P_DIM = 32;
// Q_DIM = 16 (hard-coded via float4 x4 loads)

constexpr int TI = 16;                      // i's per block
constexpr int TB = 16;                      // b's per block
constexpr int SROW = J_DIM * P_DIM + 9;     // 1033: padded LDS row stride (floats)

__device__ __forceinline__ float dot16(const float4* __restrict__ wp,
                                       const float4 xa, const float4 xb,
                                       const float4 xc, const float4 xd) {
    const float4 w0 = wp[0], w1 = wp[1], w2 = wp[2], w3 = wp[3];
    return (xa.x * w0.x + xa.y * w0.y + xa.z * w0.z + xa.w * w0.w)
         + (xb.x * w1.x + xb.y * w1.y + xb.z * w1.z + xb.w * w1.w)
         + (xc.x * w2.x + xc.y * w2.y + xc.z * w2.z + xc.w * w2.w)
         + (xd.x * w3.x + xd.y * w3.y + xd.z * w3.z + xd.w * w3.w);
}

// One routing pass over u_hat.
//   v_in == nullptr  -> first iteration: c = 1/J uniform, no b update.
//   blog_in == nullptr -> b_old = 0.
//   blog_out != nullptr -> write updated logits (needed before the next pass).
// s_out [B, J*P] is accumulated with atomicAdd (must be zeroed beforehand).
__global__ __launch_bounds__(256, 2)
void routing_pass(const float* __restrict__ x,        // [B, I, 16]
                  const float* __restrict__ W,        // [J, I, P, 16]
                  const float* __restrict__ v_in,     // [B, J, P] or null
                  const float* __restrict__ blog_in,  // [I, B, J] or null
                  float* __restrict__ blog_out,       // [I, B, J] or null
                  float* __restrict__ s_out)          // [B, J*P]
{
    __shared__ float s_local[TB * SROW];
    const int t = threadIdx.x;
    for (int k = t; k < TB * SROW; k += 256) s_local[k] = 0.f;
    __syncthreads();

    // XCD-chunked bijective swizzle (gridDim.x % 8 == 0): each XCD gets a
    // contiguous i-range so its W slice streams through its own L2.
    const int nblk = (int)gridDim.x;
    const int cpx  = nblk >> 3;
    const int bid  = (int)blockIdx.x;
    const int swz  = (bid & 7) * cpx + (bid >> 3);
    const int i_tile = swz >> 2;            // B_DIM/TB = 4 b-groups per i_tile
    const int b0     = (swz & 3) * TB;

    const int bl = t >> 4;                  // local b: 0..15 (16 lanes share b)
    const int b  = b0 + bl;
    const int pj = t & 15;                  // p-pair index: p0 = 2*pj
    const int p0 = pj << 1;

    for (int ii = 0; ii < TI; ++ii) {
        const int i = i_tile * TI + ii;

        // x[b, i, 0..15]
        const float4* xp = reinterpret_cast<const float4*>(x + ((b * I_DIM + i) << 4));
        const float4 xa = xp[0], xb = xp[1], xc = xp[2], xd = xp[3];

        // u_hat[b, j, i, p0..p0+1] for all j
        float u0[J_DIM], u1[J_DIM];
        #pragma unroll
        for (int j = 0; j < J_DIM; ++j) {
            const float4* wp = reinterpret_cast<const float4*>(
                W + (((j * I_DIM + i) * P_DIM + p0) << 4));
            u0[j] = dot16(wp,     xa, xb, xc, xd);
            u1[j] = dot16(wp + 4, xa, xb, xc, xd);
        }

        float c[J_DIM];
        if (v_in != nullptr) {
            float bnew[J_DIM];
            #pragma unroll
            for (int j = 0; j < J_DIM; ++j) {
                const float2 vv = *reinterpret_cast<const float2*>(
                    v_in + (b * J_DIM + j) * P_DIM + p0);
                float d = u0[j] * vv.x + u1[j] * vv.y;
                // sum over all 32 p: reduce across the 16-lane group (2 p each)
                d += __shfl_xor(d, 1);
                d += __shfl_xor(d, 2);
                d += __shfl_xor(d, 4);
                d += __shfl_xor(d, 8);
                const float bo = (blog_in != nullptr)
                                   ? blog_in[(i * B_DIM + b) * J_DIM + j] : 0.f;
                const float bn = bo + d;
                bnew[j] = bn;
                // each lane persists its own two j's (constant-index predicated store)
                if (blog_out != nullptr && (j >> 1) == pj) {
                    blog_out[(i * B_DIM + b) * J_DIM + j] = bn;
                }
            }
            // softmax over j (each lane redundantly; values identical in group)
            float m = bnew[0];
            #pragma unroll
            for (int j = 1; j < J_DIM; ++j) m = fmaxf(m, bnew[j]);
            float ssum = 0.f;
            #pragma unroll
            for (int j = 0; j < J_DIM; ++j) {
                const float e = __expf(bnew[j] - m);
                c[j] = e;
                ssum += e;
            }
            const float inv = 1.f / ssum;
            #pragma unroll
            for (int j = 0; j < J_DIM; ++j) c[j] *= inv;
        } else {
            #pragma unroll
            for (int j = 0; j < J_DIM; ++j) c[j] = (1.f / 32.f);
        }

        // s_local[bl, j, p] += c[j] * u_hat
        float* sl = s_local + bl * SROW + p0;
        #pragma unroll
        for (int j = 0; j < J_DIM; ++j) {
            sl[j * P_DIM]     += c[j] * u0[j];
            sl[j * P_DIM + 1] += c[j] * u1[j];
        }
    }
    __syncthreads();

    // flush block-local s to global (128 blocks contribute per element)
    for (int k = t; k < TB * J_DIM * P_DIM; k += 256) {
        const int bl2 = k >> 10;
        const int jp  = k & 1023;
        atomicAdd(&s_out[(b0 + bl2) * (J_DIM * P_DIM) + jp], s_local[bl2 * SROW + jp]);
    }
}

// v = squash(s): per (b,j) row of 32, scale = n2/(1+n2)/sqrt(n2+eps)
__global__ void squash_kernel(const float* __restrict__ s, float* __restrict__ out)
{
    const int tid = blockIdx.x * blockDim.x + threadIdx.x;  // (b*J + j)
    if (tid >= B_DIM * J_DIM) return;
    const float* sp = s + tid * P_DIM;
    float n2 = 0.f;
    #pragma unroll
    for (int p = 0; p < P_DIM; ++p) { const float xv = sp[p]; n2 += xv * xv; }
    const float scale = n2 / ((1.f + n2) * sqrtf(n2 + 1e-7f));
    float* op = out + tid * P_DIM;
    #pragma unroll
    for (int p = 0; p < P_DIM; ++p) op[p] = scale * sp[p];
}

} // namespace

extern "C" void kernel_launch(void* const* d_in, const int* in_sizes, int n_in,
                              void* d_out, int out_size, void* d_ws, size_t ws_size,
                              hipStream_t stream) {
    const float* x = (const float*)d_in[0];   // [64, 2048, 16]
    const float* W = (const float*)d_in[1];   // [32, 2048, 32, 16]
    float* out = (float*)d_out;               // [64, 32, 32]

    // workspace layout (floats)
    float* blog = (float*)d_ws;                                   // I*B*J = 4,194,304
    float* s    = blog + (size_t)I_DIM * B_DIM * J_DIM;           // B*J*P = 65,536
    float* v    = s + B_DIM * J_DIM * P_DIM;                      // B*J*P = 65,536

    const size_t s_bytes = (size_t)B_DIM * J_DIM * P_DIM * sizeof(float);
    const dim3 rgrid(512), rblk(256);
    const dim3 qgrid(8), qblk(256);

    // pass A: c uniform (1/J), s1 = sum_i c*u_hat ; v1 = squash(s1)
    hipMemsetAsync(s, 0, s_bytes, stream);
    routing_pass<<<rgrid, rblk, 0, stream>>>(x, W, nullptr, nullptr, nullptr, s);
    squash_kernel<<<qgrid, qblk, 0, stream>>>(s, v);

    // pass B: b2 = 0 + sum_p v1*u_hat ; c2 = softmax(b2) ; s2 ; v2
    hipMemsetAsync(s, 0, s_bytes, stream);
    routing_pass<<<rgrid, rblk, 0, stream>>>(x, W, v, nullptr, blog, s);
    squash_kernel<<<qgrid, qblk, 0, stream>>>(s, v);

    // pass C: b3 = b2 + sum_p v2*u_hat ; c3 = softmax(b3) ; s3 ; out = squash(s3)
    hipMemsetAsync(s, 0, s_bytes, stream);
    routing_pass<<<rgrid, rblk, 0, stream>>>(x, W, v, blog, nullptr, s);
    squash_kernel<<<qgrid, qblk, 0, stream>>>(s, out);
}

// Round 2
// 366.639 us; speedup vs baseline: 8.3437x; 8.3437x over previous
//
#include <hip/hip_runtime.h>

// DigitCaps dynamic routing, MI355X — round 2: bf16 MFMA formulation.
//
// u_hat[b,j,i,p] = sum_q x[b,i,q] W[j,i,p,q];   b=64, i=2048, j=32, p=32, q=16
// Pass A: s1 = (1/32) sum_i u_hat ; v1 = squash(s1)
// Pass B: d1 = sum_p v1*u_hat ; c2 = softmax_j(d1) ; s2 = sum_i c2*u_hat
// Pass C: b2 = d1+d2 = sum_p (v1+v2)*u_hat  -> identical kernel with v = v1+squash(s2)
//
// MFMA: 16x16x32 bf16, M=b-tile(16), N=(j*32+p) tiles of 16, K: k0-15 = x_hi,
// k16-31 = x_lo residual vs replicated W  => A-side is fp32-accurate, only W is bf16.
// W preconverted to Wt[i][n=j*32+p][q] bf16 (64MB, LLC-resident), x to
// xT2[i][b][16 hi | 16 lo] bf16. Fallback (small ws): convert W per-use from fp32.

namespace {

using bfrag = __attribute__((ext_vector_type(8))) short;   // 8 bf16 = 4 VGPR
using ffrag = __attribute__((ext_vector_type(4))) float;   // 4 fp32 accum

constexpr int I_DIM = 2048;
constexpr int B_DIM = 64;
constexpr int N_DIM = 1024;   // j*32+p
constexpr int TI    = 16;     // i's per block

__device__ __forceinline__ unsigned short f2bf(float f) {
    unsigned int u = __float_as_uint(f);
    unsigned int r = (u + 0x7fffu + ((u >> 16) & 1u)) >> 16;
    return (unsigned short)r;
}

// ---------------- conversion kernels ----------------

// Wt[i][n][q] bf16  <-  W[j][i][p][q] fp32   (n = j*32+p)
__global__ __launch_bounds__(256)
void conv_w(const float* __restrict__ W, unsigned short* __restrict__ Wt) {
    const int t = blockIdx.x * 256 + threadIdx.x;          // (i,n), 2M threads
    const int i = t >> 10, n = t & 1023;
    const float* src = W + ((((n >> 5) * I_DIM + i) * 32 + (n & 31)) << 4);
    unsigned int o[8];
    #pragma unroll
    for (int k = 0; k < 8; ++k)
        o[k] = (unsigned int)f2bf(src[2 * k]) | ((unsigned int)f2bf(src[2 * k + 1]) << 16);
    uint4* dst = reinterpret_cast<uint4*>(Wt + (size_t)t * 16);
    dst[0] = make_uint4(o[0], o[1], o[2], o[3]);
    dst[1] = make_uint4(o[4], o[5], o[6], o[7]);
}

// xT2[i][b][0:16]=hi(x), [16:32]=lo residual  <-  x[b][i][q] fp32
__global__ __launch_bounds__(256)
void conv_x(const float* __restrict__ x, unsigned short* __restrict__ xT2) {
    const int t = blockIdx.x * 256 + threadIdx.x;          // (i,b), 128K threads
    const int i = t >> 6, b = t & 63;
    const float* src = x + (((size_t)b * I_DIM + i) << 4);
    unsigned int o[16];
    #pragma unroll
    for (int k = 0; k < 8; ++k) {
        const float f0 = src[2 * k], f1 = src[2 * k + 1];
        const unsigned short h0 = f2bf(f0), h1 = f2bf(f1);
        const float l0 = f0 - __uint_as_float(((unsigned int)h0) << 16);
        const float l1 = f1 - __uint_as_float(((unsigned int)h1) << 16);
        o[k]     = (unsigned int)h0       | ((unsigned int)h1 << 16);
        o[8 + k] = (unsigned int)f2bf(l0) | ((unsigned int)f2bf(l1) << 16);
    }
    uint4* dst = reinterpret_cast<uint4*>(xT2 + (size_t)t * 32);
    #pragma unroll
    for (int k = 0; k < 4; ++k)
        dst[k] = make_uint4(o[4 * k], o[4 * k + 1], o[4 * k + 2], o[4 * k + 3]);
}

// ---------------- routing pass ----------------
// Block: 512 thr = 8 waves; covers one 16-b group x all 1024 n for TI i's.
// Wave w owns j in [4w, 4w+4) => 8 N-tiles (jj 0..3  x  p-half 0..1).
// ROUTED: per i, cross-wave softmax over j via LDS (2 barriers).
template<bool ROUTED, bool WT>
__global__ __launch_bounds__(512)
void caps_pass(const unsigned short* __restrict__ Wt,   // [I][N][16] bf16 (WT)
               const float* __restrict__ Wf,            // [J][I][P][Q] fp32 (!WT)
               const unsigned short* __restrict__ xT2,  // [I][64][32] bf16
               const float* __restrict__ v_in,          // [64][32][32] or null
               float* __restrict__ s_out)               // [64][1024]
{
    __shared__ float d_buf[16 * 33];
    __shared__ float c_buf[16 * 33];

    const int tid = threadIdx.x;
    const int w   = tid >> 6;          // wave 0..7
    const int l   = tid & 63;
    const int g   = l >> 4;            // 16-lane group 0..3
    const int li  = l & 15;
    const int j0  = w << 2;
    const int qb  = (g & 1) << 3;      // q base 0/8 (W replicated across k-halves)

    // XCD-chunked swizzle: blocks with same i-tile land on one XCD.
    const int bid = (int)blockIdx.x;
    const int V   = (bid & 7) * 64 + (bid >> 3);
    const int it  = V >> 2;
    const int b0  = (V & 3) << 4;

    // v registers: vr[r][tile] = v[b0+4g+r][j0+(t>>1)][(t&1)*16+li]
    float vr[4][8];
    if (ROUTED) {
        #pragma unroll
        for (int r = 0; r < 4; ++r)
            #pragma unroll
            for (int t = 0; t < 8; ++t)
                vr[r][t] = v_in[((b0 + (g << 2) + r) * 32 + j0 + (t >> 1)) * 32
                                + ((t & 1) << 4) + li];
    }

    ffrag s[8];
    #pragma unroll
    for (int t = 0; t < 8; ++t) s[t] = ffrag{0.f, 0.f, 0.f, 0.f};

    for (int i = it * TI; i < it * TI + TI; ++i) {
        // A-frag: groups 0,1 = hi(q0-7, q8-15); groups 2,3 = lo residual
        const bfrag a = *reinterpret_cast<const bfrag*>(
            xT2 + (((size_t)i << 6) + b0 + li) * 32 + ((g >> 1) << 4) + qb);

        ffrag u[8];
        #pragma unroll
        for (int t = 0; t < 8; ++t) {
            const int n0 = (j0 + (t >> 1)) * 32 + ((t & 1) << 4);
            bfrag bf;
            if (WT) {
                bf = *reinterpret_cast<const bfrag*>(
                    Wt + (((size_t)i << 10) + n0 + li) * 16 + qb);
            } else {
                const int n = n0 + li;
                const float* wp = Wf + ((((size_t)(n >> 5) * I_DIM + i) * 32 + (n & 31)) << 4) + qb;
                #pragma unroll
                for (int e = 0; e < 8; ++e) bf[e] = (short)f2bf(wp[e]);
            }
            ffrag z{0.f, 0.f, 0.f, 0.f};
            u[t] = __builtin_amdgcn_mfma_f32_16x16x32_bf16(a, bf, z, 0, 0, 0);
        }

        if (ROUTED) {
            // d[b,j] partials: per lane 2 p-contributions, then 16-lane p-reduce
            float dd[4][4];
            #pragma unroll
            for (int r = 0; r < 4; ++r)
                #pragma unroll
                for (int jj = 0; jj < 4; ++jj) {
                    float dv = u[2 * jj][r] * vr[r][2 * jj]
                             + u[2 * jj + 1][r] * vr[r][2 * jj + 1];
                    dv += __shfl_xor(dv, 1);
                    dv += __shfl_xor(dv, 2);
                    dv += __shfl_xor(dv, 4);
                    dv += __shfl_xor(dv, 8);
                    dd[r][jj] = dv;
                }
            #pragma unroll
            for (int jj = 0; jj < 4; ++jj)
                if (li == jj) {
                    #pragma unroll
                    for (int r = 0; r < 4; ++r)
                        d_buf[((g << 2) + r) * 33 + j0 + jj] = dd[r][jj];
                }
            __syncthreads();

            // softmax over j: thread (bl = tid>>5, jx = tid&31)
            const int bl = tid >> 5, jx = tid & 31;
            const float bn = d_buf[bl * 33 + jx];
            float mx = bn;
            mx = fmaxf(mx, __shfl_xor(mx, 16));
            mx = fmaxf(mx, __shfl_xor(mx, 8));
            mx = fmaxf(mx, __shfl_xor(mx, 4));
            mx = fmaxf(mx, __shfl_xor(mx, 2));
            mx = fmaxf(mx, __shfl_xor(mx, 1));
            const float e = __expf(bn - mx);
            float sm = e;
            sm += __shfl_xor(sm, 16);
            sm += __shfl_xor(sm, 8);
            sm += __shfl_xor(sm, 4);
            sm += __shfl_xor(sm, 2);
            sm += __shfl_xor(sm, 1);
            c_buf[bl * 33 + jx] = e / sm;
            __syncthreads();

            // s += c * u
            float cr[4][4];
            #pragma unroll
            for (int r = 0; r < 4; ++r)
                #pragma unroll
                for (int jj = 0; jj < 4; ++jj)
                    cr[r][jj] = c_buf[((g << 2) + r) * 33 + j0 + jj];
            #pragma unroll
            for (int t = 0; t < 8; ++t)
                #pragma unroll
                for (int r = 0; r < 4; ++r)
                    s[t][r] += cr[r][t >> 1] * u[t][r];
        } else {
            #pragma unroll
            for (int t = 0; t < 8; ++t) s[t] += u[t];
        }
    }

    const float sc = ROUTED ? 1.f : (1.f / 32.f);
    #pragma unroll
    for (int t = 0; t < 8; ++t) {
        const int n0 = (j0 + (t >> 1)) * 32 + ((t & 1) << 4);
        #pragma unroll
        for (int r = 0; r < 4; ++r)
            atomicAdd(&s_out[(b0 + (g << 2) + r) * N_DIM + n0 + li], s[t][r] * sc);
    }
}

// dst[row] = (base ? base[row] : 0) + squash(s[row]),  row = (b,j), 32 p's
__global__ __launch_bounds__(256)
void squash_add(const float* __restrict__ s, const float* __restrict__ base,
                float* __restrict__ dst) {
    const int t = blockIdx.x * 256 + threadIdx.x;
    if (t >= B_DIM * 32) return;
    const float* sp = s + t * 32;
    float n2 = 0.f;
    #pragma unroll
    for (int p = 0; p < 32; ++p) { const float xv = sp[p]; n2 += xv * xv; }
    const float scl = n2 / ((1.f + n2) * sqrtf(n2 + 1e-7f));
    float* op = dst + t * 32;
    #pragma unroll
    for (int p = 0; p < 32; ++p)
        op[p] = (base ? base[t * 32 + p] : 0.f) + scl * sp[p];
}

} // namespace

extern "C" void kernel_launch(void* const* d_in, const int* in_sizes, int n_in,
                              void* d_out, int out_size, void* d_ws, size_t ws_size,
                              hipStream_t stream) {
    const float* x = (const float*)d_in[0];   // [64, 2048, 16]
    const float* W = (const float*)d_in[1];   // [32, 2048, 32, 16]
    float* out = (float*)d_out;               // [64, 32, 32]

    const size_t needW = (size_t)I_DIM * N_DIM * 16 * 2;   // 64 MB bf16 Wt
    const size_t needX = (size_t)I_DIM * B_DIM * 32 * 2;   // 8 MB bf16 xT2
    const size_t needS = (size_t)B_DIM * N_DIM * 4;        // 256 KB
    const bool wt = ws_size >= needW + needX + 3 * needS;

    char* p = (char*)d_ws;
    unsigned short* Wt = nullptr;
    if (wt) { Wt = (unsigned short*)p; p += needW; }
    unsigned short* xT2 = (unsigned short*)p; p += needX;
    float* s  = (float*)p; p += needS;
    float* v1 = (float*)p; p += needS;
    float* vs = (float*)p;

    conv_x<<<(I_DIM * B_DIM) / 256, 256, 0, stream>>>(x, xT2);
    if (wt) conv_w<<<(I_DIM * N_DIM) / 256, 256, 0, stream>>>(W, Wt);

    const dim3 rg(512), rb(512);

    // pass A
    hipMemsetAsync(s, 0, needS, stream);
    if (wt) caps_pass<false, true ><<<rg, rb, 0, stream>>>(Wt, nullptr, xT2, nullptr, s);
    else    caps_pass<false, false><<<rg, rb, 0, stream>>>(nullptr, W, xT2, nullptr, s);
    squash_add<<<8, 256, 0, stream>>>(s, nullptr, v1);

    // pass B (v = v1)
    hipMemsetAsync(s, 0, needS, stream);
    if (wt) caps_pass<true, true ><<<rg, rb, 0, stream>>>(Wt, nullptr, xT2, v1, s);
    else    caps_pass<true, false><<<rg, rb, 0, stream>>>(nullptr, W, xT2, v1, s);
    squash_add<<<8, 256, 0, stream>>>(s, v1, vs);   // vs = v1 + squash(s2) = v1+v2

    // pass C (v = v1+v2 since b2 = d1+d2 is linear in v)
    hipMemsetAsync(s, 0, needS, stream);
    if (wt) caps_pass<true, true ><<<rg, rb, 0, stream>>>(Wt, nullptr, xT2, vs, s);
    else    caps_pass<true, false><<<rg, rb, 0, stream>>>(nullptr, W, xT2, vs, s);
    squash_add<<<8, 256, 0, stream>>>(s, nullptr, out);
}

// Round 3
// 255.511 us; speedup vs baseline: 11.9726x; 1.4349x over previous
//
#include <hip/hip_runtime.h>

// DigitCaps dynamic routing, MI355X — round 3.
// Changes vs round 2: DPP row_ror reductions (no ds_swizzle), raw s_barrier
// (lgkmcnt-only drain -> prefetch survives), explicit next-i frag prefetch,
// 1024-thr blocks with 2 j per wave (v in 16 regs, LDS ops ~16/wave-i).
//
// u_hat[b,j,i,p] = sum_q x[b,i,q] W[j,i,p,q];  b=64, i=2048, j=32, p=32, q=16
// Pass A: s1 = (1/32) sum_i u_hat ; v1 = squash(s1)
// Pass B: d1 = sum_p v1*u_hat ; c2 = softmax_j(d1) ; s2 ; v2 = squash(s2)
// Pass C: b3 = d1+d2 = sum_p (v1+v2)*u_hat  (linearity) ; out = squash(s3)
//
// MFMA 16x16x32 bf16: M=16 b, N=16 n (n=j*32+p), K: k0-15 = x_hi, k16-31 =
// x_lo residual vs k-replicated W => A-side fp32-exact, only W rounded.

namespace {

using bfrag = __attribute__((ext_vector_type(8))) short;   // 8 bf16 = 4 VGPR
using ffrag = __attribute__((ext_vector_type(4))) float;   // 4 fp32 acc

constexpr int I_DIM = 2048;
constexpr int B_DIM = 64;
constexpr int N_DIM = 1024;   // j*32+p
constexpr int TI    = 16;     // i's per block

__device__ __forceinline__ unsigned short f2bf(float f) {
    unsigned int u = __float_as_uint(f);
    unsigned int r = (u + 0x7fffu + ((u >> 16) & 1u)) >> 16;
    return (unsigned short)r;
}

// DPP helpers: row_ror:k within 16-lane rows — pure VALU, no LDS pipe.
template<int CTRL>
__device__ __forceinline__ float dppf(float x) {
    return __int_as_float(
        __builtin_amdgcn_update_dpp(0, __float_as_int(x), CTRL, 0xF, 0xF, true));
}
__device__ __forceinline__ float sum16(float x) {   // all 16 lanes get total
    x += dppf<0x121>(x);   // row_ror:1
    x += dppf<0x122>(x);   // row_ror:2
    x += dppf<0x124>(x);   // row_ror:4
    x += dppf<0x128>(x);   // row_ror:8
    return x;
}
__device__ __forceinline__ float max16(float x) {
    x = fmaxf(x, dppf<0x121>(x));
    x = fmaxf(x, dppf<0x122>(x));
    x = fmaxf(x, dppf<0x124>(x));
    x = fmaxf(x, dppf<0x128>(x));
    return x;
}

// ---------------- conversion kernels (validated round 2) ----------------

__global__ __launch_bounds__(256)
void conv_w(const float* __restrict__ W, unsigned short* __restrict__ Wt) {
    const int t = blockIdx.x * 256 + threadIdx.x;          // (i,n)
    const int i = t >> 10, n = t & 1023;
    const float* src = W + ((((n >> 5) * I_DIM + i) * 32 + (n & 31)) << 4);
    unsigned int o[8];
    #pragma unroll
    for (int k = 0; k < 8; ++k)
        o[k] = (unsigned int)f2bf(src[2 * k]) | ((unsigned int)f2bf(src[2 * k + 1]) << 16);
    uint4* dst = reinterpret_cast<uint4*>(Wt + (size_t)t * 16);
    dst[0] = make_uint4(o[0], o[1], o[2], o[3]);
    dst[1] = make_uint4(o[4], o[5], o[6], o[7]);
}

__global__ __launch_bounds__(256)
void conv_x(const float* __restrict__ x, unsigned short* __restrict__ xT2) {
    const int t = blockIdx.x * 256 + threadIdx.x;          // (i,b)
    const int i = t >> 6, b = t & 63;
    const float* src = x + (((size_t)b * I_DIM + i) << 4);
    unsigned int o[16];
    #pragma unroll
    for (int k = 0; k < 8; ++k) {
        const float f0 = src[2 * k], f1 = src[2 * k + 1];
        const unsigned short h0 = f2bf(f0), h1 = f2bf(f1);
        const float l0 = f0 - __uint_as_float(((unsigned int)h0) << 16);
        const float l1 = f1 - __uint_as_float(((unsigned int)h1) << 16);
        o[k]     = (unsigned int)h0       | ((unsigned int)h1 << 16);
        o[8 + k] = (unsigned int)f2bf(l0) | ((unsigned int)f2bf(l1) << 16);
    }
    uint4* dst = reinterpret_cast<uint4*>(xT2 + (size_t)t * 32);
    #pragma unroll
    for (int k = 0; k < 4; ++k)
        dst[k] = make_uint4(o[4 * k], o[4 * k + 1], o[4 * k + 2], o[4 * k + 3]);
}

// ---------------- routing pass ----------------
// Block: 1024 thr = 16 waves, one 16-b group, all 32 j (2 j per wave), TI i's.
// Wave w: j = {2w, 2w+1}; tiles t = jj*2+ph (jj=t>>1, p-half ph=t&1).
#define LOAD_FRAGS(iv)                                                          \
    do {                                                                        \
        const int i_ = (iv);                                                    \
        af = *reinterpret_cast<const bfrag*>(                                   \
            xT2 + (((size_t)i_ << 6) + b0 + li) * 32 + g8);                     \
        _Pragma("unroll")                                                       \
        for (int t = 0; t < 4; ++t)                                             \
            bfr[t] = *reinterpret_cast<const bfrag*>(                           \
                Wt + (((size_t)i_ << 10) + ((j0 + (t >> 1)) << 5)               \
                      + ((t & 1) << 4) + li) * 16 + qb);                        \
    } while (0)

template<bool ROUTED>
__global__ __launch_bounds__(1024, 4)
void caps_pass(const unsigned short* __restrict__ Wt,   // [I][N][16] bf16
               const unsigned short* __restrict__ xT2,  // [I][64][32] bf16
               const float* __restrict__ v_in,          // [64][32][32] or null
               float* __restrict__ s_out)               // [64][1024]
{
    __shared__ float d_buf[16 * 33];
    __shared__ float c_buf[16 * 33];

    const int tid = threadIdx.x;
    const int w   = tid >> 6;          // wave 0..15
    const int l   = tid & 63;
    const int g   = l >> 4;            // 16-lane group 0..3
    const int li  = l & 15;
    const int j0  = w << 1;            // 2 j per wave
    const int qb  = (g & 1) << 3;      // B k-replication: q base 0/8
    const int g8  = g << 3;            // A k offset = 8g (hi 0-15, lo 16-31)

    // XCD-chunked bijective swizzle (512 blocks): same-i_tile blocks adjacent.
    const int bid = (int)blockIdx.x;
    const int V   = (bid & 7) * 64 + (bid >> 3);
    const int it  = V >> 2;
    const int b0  = (V & 3) << 4;

    // v in registers: vr[r][t] = v[b0+4g+r][j0+(t>>1)][(t&1)*16+li]
    float vr[4][4];
    if (ROUTED) {
        #pragma unroll
        for (int r = 0; r < 4; ++r)
            #pragma unroll
            for (int t = 0; t < 4; ++t)
                vr[r][t] = v_in[((b0 + (g << 2) + r) * 32 + j0 + (t >> 1)) * 32
                                + ((t & 1) << 4) + li];
    }

    bfrag af;
    bfrag bfr[4];
    LOAD_FRAGS(it * TI);               // prologue: frags for first i

    ffrag s[4];
    #pragma unroll
    for (int t = 0; t < 4; ++t) s[t] = ffrag{0.f, 0.f, 0.f, 0.f};

    for (int ii = 0; ii < TI; ++ii) {
        // u from current frags (loaded last iteration / prologue)
        ffrag u[4];
        #pragma unroll
        for (int t = 0; t < 4; ++t) {
            ffrag z{0.f, 0.f, 0.f, 0.f};
            u[t] = __builtin_amdgcn_mfma_f32_16x16x32_bf16(af, bfr[t], z, 0, 0, 0);
        }

        // prefetch next i (clamped: last iter reloads same i, harmless);
        // clobber pins the issue point so loads stay ahead of the barriers.
        LOAD_FRAGS(it * TI + ((ii + 1 < TI) ? (ii + 1) : ii));
        asm volatile("" ::: "memory");

        if (ROUTED) {
            // d[b,j] = sum_p v*u : in-lane 2 FMA per jj, DPP 16-lane reduce
            float dsel[4];
            #pragma unroll
            for (int r = 0; r < 4; ++r) {
                float d0 = u[0][r] * vr[r][0] + u[1][r] * vr[r][1];
                float d1 = u[2][r] * vr[r][2] + u[3][r] * vr[r][3];
                d0 = sum16(d0);
                d1 = sum16(d1);
                dsel[r] = (li & 1) ? d1 : d0;
            }
            #pragma unroll
            for (int r = 0; r < 4; ++r)
                if (li < 2) d_buf[((g << 2) + r) * 33 + j0 + li] = dsel[r];

            // raw barrier: drain LDS only — global prefetch stays in flight
            asm volatile("s_waitcnt lgkmcnt(0)\n\ts_barrier" ::: "memory");

            // softmax over j: threads 0..511 -> (bl = tid>>5, jx = tid&31)
            if (tid < 512) {
                const int bl = tid >> 5, jx = tid & 31;
                const float bn = d_buf[bl * 33 + jx];
                float m = max16(bn);
                m = fmaxf(m, __shfl_xor(m, 16));
                const float e = __expf(bn - m);
                float ssum = sum16(e);
                ssum += __shfl_xor(ssum, 16);
                c_buf[bl * 33 + jx] = e / ssum;
            }

            asm volatile("s_waitcnt lgkmcnt(0)\n\ts_barrier" ::: "memory");

            // s += c * u  (broadcast c reads: 8 per wave-i)
            #pragma unroll
            for (int r = 0; r < 4; ++r) {
                const float c0 = c_buf[((g << 2) + r) * 33 + j0];
                const float c1 = c_buf[((g << 2) + r) * 33 + j0 + 1];
                s[0][r] += c0 * u[0][r];
                s[1][r] += c0 * u[1][r];
                s[2][r] += c1 * u[2][r];
                s[3][r] += c1 * u[3][r];
            }
        } else {
            #pragma unroll
            for (int t = 0; t < 4; ++t) s[t] += u[t];
        }
    }

    const float sc = ROUTED ? 1.f : (1.f / 32.f);
    #pragma unroll
    for (int t = 0; t < 4; ++t)
        #pragma unroll
        for (int r = 0; r < 4; ++r)
            atomicAdd(&s_out[(b0 + (g << 2) + r) * N_DIM
                             + ((j0 + (t >> 1)) << 5) + ((t & 1) << 4) + li],
                      s[t][r] * sc);
}

// dst[row] = (base ? base[row] : 0) + squash(s[row]),  row = (b,j)
__global__ __launch_bounds__(256)
void squash_add(const float* __restrict__ s, const float* __restrict__ base,
                float* __restrict__ dst) {
    const int t = blockIdx.x * 256 + threadIdx.x;
    if (t >= B_DIM * 32) return;
    const float* sp = s + t * 32;
    float n2 = 0.f;
    #pragma unroll
    for (int p = 0; p < 32; ++p) { const float xv = sp[p]; n2 += xv * xv; }
    const float scl = n2 / ((1.f + n2) * sqrtf(n2 + 1e-7f));
    float* op = dst + t * 32;
    #pragma unroll
    for (int p = 0; p < 32; ++p)
        op[p] = (base ? base[t * 32 + p] : 0.f) + scl * sp[p];
}

} // namespace

extern "C" void kernel_launch(void* const* d_in, const int* in_sizes, int n_in,
                              void* d_out, int out_size, void* d_ws, size_t ws_size,
                              hipStream_t stream) {
    const float* x = (const float*)d_in[0];   // [64, 2048, 16]
    const float* W = (const float*)d_in[1];   // [32, 2048, 32, 16]
    float* out = (float*)d_out;               // [64, 32, 32]

    const size_t needW = (size_t)I_DIM * N_DIM * 16 * 2;   // 64 MB bf16 Wt
    const size_t needX = (size_t)I_DIM * B_DIM * 32 * 2;   // 8 MB bf16 xT2
    const size_t needS = (size_t)B_DIM * N_DIM * 4;        // 256 KB

    char* p = (char*)d_ws;
    unsigned short* Wt  = (unsigned short*)p; p += needW;
    unsigned short* xT2 = (unsigned short*)p; p += needX;
    float* s  = (float*)p; p += needS;
    float* v1 = (float*)p; p += needS;
    float* vs = (float*)p;

    conv_x<<<(I_DIM * B_DIM) / 256, 256, 0, stream>>>(x, xT2);
    conv_w<<<(I_DIM * N_DIM) / 256, 256, 0, stream>>>(W, Wt);

    const dim3 rg(512), rb(1024);

    // pass A: uniform c = 1/32
    hipMemsetAsync(s, 0, needS, stream);
    caps_pass<false><<<rg, rb, 0, stream>>>(Wt, xT2, nullptr, s);
    squash_add<<<8, 256, 0, stream>>>(s, nullptr, v1);

    // pass B: v = v1
    hipMemsetAsync(s, 0, needS, stream);
    caps_pass<true><<<rg, rb, 0, stream>>>(Wt, xT2, v1, s);
    squash_add<<<8, 256, 0, stream>>>(s, v1, vs);          // vs = v1 + v2

    // pass C: v = v1+v2 (b3 = d1+d2 is linear in v)
    hipMemsetAsync(s, 0, needS, stream);
    caps_pass<true><<<rg, rb, 0, stream>>>(Wt, xT2, vs, s);
    squash_add<<<8, 256, 0, stream>>>(s, nullptr, out);
}